// Round 19
// baseline (40.576 us; speedup 1.0000x reference)
//
#include <hip/hip_runtime.h>

// Problem constants (B=8, K=32 -> N=256 patches; C=3; H=W=128)
#define HH 128
#define WW 128
#define HW (HH * WW)
#define BAND 16            // output rows per band
#define TROWS 18           // intermediate tile rows (nrows <= 18 proven)

// ---------------------------------------------------------------------------
// Correctness split (R9-R18 verified):
//  - LABELS (nearest): bit-exact chain (CR f32 trig, XLA-FMA rotation,
//    stepwise pix chain, rintf). UNTOUCHED.
//  - PATCHES (bilinear): continuous in coords; fast affine forms safe
//    (absmax 0.008-0.016 vs threshold 0.069).
// Structure (R16+): full 64 KB slice in LDS (1x fetch), 8 banded passes.
// This round: wave-uniform INTERIOR fast paths. Per intermediate row, a
// scalar range test (affine: ix = midx + P*(w-63.5), extremes at w=0/127)
// proves all taps interior -> mask-free, clamp-free lerp body. Borderline
// rows (0.25 px margin) use the full masked path. Pass-2: per-band fast2
// (lo/hi unclamped => yi,yi+1 always inside the band; no y masks/clamps).
// ---------------------------------------------------------------------------

__device__ __forceinline__ float norm_coord(int i) {
    return __fsub_rn(__fmul_rn((float)(2 * i + 1), 0.0078125f), 1.0f);
}

__device__ __forceinline__ float pix_coord(float g) {
    float t = __fadd_rn(g, 1.0f);
    t = __fmul_rn(t, 128.0f);
    t = __fsub_rn(t, 1.0f);
    return __fmul_rn(t, 0.5f);
}

__device__ __forceinline__ int med127(int v) {
    return min(max(v, 0), 127);     // -> v_med3_i32
}

__global__ void __launch_bounds__(1024, 8)
pa_all(const float* __restrict__ patches,
       const float* __restrict__ labels,
       const float* __restrict__ angles,
       const int* __restrict__ flip_h,
       const int* __restrict__ flip_v,
       const float* __restrict__ scales,
       float* __restrict__ out_p,
       float* __restrict__ out_l,
       int npatch_blocks) {
    __shared__ float src[HW];               // 64 KB full source slice
    __shared__ float tile[TROWS * WW];      // 9 KB pass-1 intermediate band
    __shared__ float prm[5];
    int bid = blockIdx.x;
    int tid = threadIdx.x;
    bool is_patch = bid < npatch_blocks;
    int n = is_patch ? (bid / 3) : (bid - npatch_blocks);

    if (tid == 0) {
        double a = (double)angles[n];
        prm[0] = (float)cos(a);             // correctly-rounded f32
        prm[1] = (float)sin(a);
        prm[2] = flip_h[n] ? -1.0f : 1.0f;
        prm[3] = flip_v[n] ? -1.0f : 1.0f;
        prm[4] = scales[n];
    }
    __syncthreads();
    float c = prm[0], s = prm[1], fsx = prm[2], fsy = prm[3], sc = prm[4];

    if (is_patch) {
        int slice = bid;                    // n*3 + ch

        // ---- stage full slice coalesced (float4, exactly 1x fetch) ----
        const float4* g4 = (const float4*)(patches + (size_t)slice * HW);
        float4* s4 = (float4*)src;
        #pragma unroll
        for (int i = 0; i < HW / 4 / 1024; ++i)      // 4 iters
            s4[i * 1024 + tid] = g4[i * 1024 + tid];

        // ---- block-uniform affine: ix = 63.5 + P*(w-63.5) + Q*(h-63.5) ----
        float P = c * fsx, Q = -s * fsy;
        float R = s * fsx, S = c * fsy;
        float P635 = fabsf(P) * 63.5f, R635 = fabsf(R) * 63.5f;

        // ---- pass-1 lane hoists ----
        int w = tid & (WW - 1);
        float wm = (float)w - 63.5f;
        int p1row = tid >> 7;               // 0..7

        // ---- pass-2 lane hoists (2 px/thread, x-side pre-masked) ----
        int w2 = (tid & 63) * 2;
        int prow = tid >> 6;                // 0..15
        float wx0a, wx1a, wx0b, wx1b;
        int xc0a, xc1a, xc0b, xc1b;
        {
            float ixo = fmaf(sc, (float)w2 - 63.5f, 63.5f);
            float xf = floorf(ixo);
            float fx = ixo - xf;
            int xi = (int)xf;
            wx0a = ((unsigned)xi < 128u) ? (1.0f - fx) : 0.0f;
            wx1a = ((unsigned)(xi + 1) < 128u) ? fx : 0.0f;
            xc0a = med127(xi); xc1a = med127(xi + 1);
            float ixo2 = ixo + sc;
            float xf2 = floorf(ixo2);
            float fx2 = ixo2 - xf2;
            int xi2 = (int)xf2;
            wx0b = ((unsigned)xi2 < 128u) ? (1.0f - fx2) : 0.0f;
            wx1b = ((unsigned)(xi2 + 1) < 128u) ? fx2 : 0.0f;
            xc0b = med127(xi2); xc1b = med127(xi2 + 1);
        }
        __syncthreads();

        float* op = out_p + (size_t)slice * HW;

        #pragma unroll
        for (int band = 0; band < HH / BAND; ++band) {       // 8 bands
            int r0 = band * BAND;
            float lof = floorf(fmaf(sc, (float)r0 - 63.5f, 63.5f));
            float hif = floorf(fmaf(sc, (float)(r0 + BAND - 1) - 63.5f, 63.5f)) + 1.0f;
            int lo = max((int)lof, 0);
            int hi = min((int)hif, 127);
            bool fast2 = (lof >= 0.0f) && (hif <= 127.0f);
            int nrows = hi - lo + 1;                         // <= 18

            // ---- pass 1: rotate+flip from LDS src -> tile ----
            #pragma unroll
            for (int it = 0; it < 3; ++it) {
                int row = it * 8 + p1row;
                if (row < nrows) {
                    float hf = (float)(lo + row) - 63.5f;
                    float midx = fmaf(Q, hf, 63.5f);
                    float midy = fmaf(S, hf, 63.5f);
                    float ix = fmaf(P, wm, midx);
                    float iy = fmaf(R, wm, midy);
                    float xf = floorf(ix), yf = floorf(iy);
                    float fx = ix - xf, fy = iy - yf;
                    int xi = (int)xf, yi = (int)yf;
                    bool fast1 = (midx - P635 >= 0.25f) && (midx + P635 <= 126.75f) &&
                                 (midy - R635 >= 0.25f) && (midy + R635 <= 126.75f);
                    float o;
                    if (fast1) {
                        int b = yi * WW + xi;
                        float v00 = src[b], v10 = src[b + 1];
                        float v01 = src[b + WW], v11 = src[b + WW + 1];
                        float ra = fmaf(fx, v10 - v00, v00);
                        float rb = fmaf(fx, v11 - v01, v01);
                        o = fmaf(fy, rb - ra, ra);
                    } else {
                        float wx0 = ((unsigned)xi < 128u) ? (1.0f - fx) : 0.0f;
                        float wx1 = ((unsigned)(xi + 1) < 128u) ? fx : 0.0f;
                        float wy0 = ((unsigned)yi < 128u) ? (1.0f - fy) : 0.0f;
                        float wy1 = ((unsigned)(yi + 1) < 128u) ? fy : 0.0f;
                        int xc0 = med127(xi), xc1 = med127(xi + 1);
                        int b0 = med127(yi) * WW, b1 = med127(yi + 1) * WW;
                        float v00 = src[b0 + xc0];
                        float v10 = src[b0 + xc1];
                        float v01 = src[b1 + xc0];
                        float v11 = src[b1 + xc1];
                        float ra = fmaf(wx1, v10, wx0 * v00);
                        float rb = fmaf(wx1, v11, wx0 * v01);
                        o = fmaf(rb, wy1, ra * wy0);
                    }
                    tile[row * WW + w] = o;
                }
            }
            __syncthreads();

            // ---- pass 2: scale from tile, 2 px/thread, float2 store ----
            {
                int h = r0 + prow;
                float iy = fmaf(sc, (float)h - 63.5f, 63.5f);
                float yf = floorf(iy);
                float fy = iy - yf;
                int yi = (int)yf;
                float ox, oy;
                if (fast2) {
                    int t0 = (yi - lo) * WW, t1 = t0 + WW;
                    float a00 = tile[t0 + xc0a], a10 = tile[t0 + xc1a];
                    float a01 = tile[t1 + xc0a], a11 = tile[t1 + xc1a];
                    float b00 = tile[t0 + xc0b], b10 = tile[t0 + xc1b];
                    float b01 = tile[t1 + xc0b], b11 = tile[t1 + xc1b];
                    float ra = fmaf(wx1a, a10, wx0a * a00);
                    float rb = fmaf(wx1a, a11, wx0a * a01);
                    ox = fmaf(fy, rb - ra, ra);
                    float rc = fmaf(wx1b, b10, wx0b * b00);
                    float rd = fmaf(wx1b, b11, wx0b * b01);
                    oy = fmaf(fy, rd - rc, rc);
                } else {
                    float wy0 = ((unsigned)yi < 128u) ? (1.0f - fy) : 0.0f;
                    float wy1 = ((unsigned)(yi + 1) < 128u) ? fy : 0.0f;
                    int t0 = (min(max(yi, lo), hi) - lo) * WW;
                    int t1 = (min(max(yi + 1, lo), hi) - lo) * WW;
                    float a00 = tile[t0 + xc0a], a10 = tile[t0 + xc1a];
                    float a01 = tile[t1 + xc0a], a11 = tile[t1 + xc1a];
                    float b00 = tile[t0 + xc0b], b10 = tile[t0 + xc1b];
                    float b01 = tile[t1 + xc0b], b11 = tile[t1 + xc1b];
                    float ra = fmaf(wx1a, a10, wx0a * a00);
                    float rb = fmaf(wx1a, a11, wx0a * a01);
                    ox = fmaf(rb, wy1, ra * wy0);
                    float rc = fmaf(wx1b, b10, wx0b * b00);
                    float rd = fmaf(wx1b, b11, wx0b * b01);
                    oy = fmaf(rd, wy1, rc * wy0);
                }
                float2 o2;
                o2.x = ox;
                o2.y = oy;
                *(float2*)&op[h * WW + w2] = o2;
            }
            __syncthreads();   // tile reused by next band
        }
    } else {
        // ----- label path: BIT-EXACT fused nearest-of-nearest (R9 chain) -----
        const float* lab = labels + (size_t)n * HW;
        float* ol = out_l + (size_t)n * HW;
        int w = tid & (WW - 1);

        float ix2 = pix_coord(__fmul_rn(sc, norm_coord(w)));
        float xr2 = rintf(ix2);
        bool okx2 = (xr2 >= 0.0f) && (xr2 <= 127.0f);
        int w2 = (int)xr2;
        float xw2 = okx2 ? __fmul_rn(fsx, norm_coord(w2)) : 0.0f;
        float cx = __fmul_rn(c, xw2);
        float sx = __fmul_rn(s, xw2);

        #pragma unroll 4
        for (int i = 0; i < HW / 1024; ++i) {        // 16 iters
            int p = i * 1024 + tid;
            int h = p >> 7;
            float iy2 = pix_coord(__fmul_rn(sc, norm_coord(h)));
            float yr2 = rintf(iy2);
            float outv = 0.0f;
            if (okx2 && yr2 >= 0.0f && yr2 <= 127.0f) {
                int h2 = (int)yr2;
                float y = __fmul_rn(fsy, norm_coord(h2));
                float xr1 = rintf(pix_coord(__fmaf_rn(-s, y, cx)));
                float yr1 = rintf(pix_coord(__fmaf_rn(c, y, sx)));
                if (xr1 >= 0.0f && xr1 <= 127.0f &&
                    yr1 >= 0.0f && yr1 <= 127.0f) {
                    outv = lab[(int)yr1 * WW + (int)xr1];
                }
            }
            ol[p] = outv;
        }
    }
}

extern "C" void kernel_launch(void* const* d_in, const int* in_sizes, int n_in,
                              void* d_out, int out_size, void* d_ws, size_t ws_size,
                              hipStream_t stream) {
    const float* patches = (const float*)d_in[0];
    const float* labels  = (const float*)d_in[1];
    const float* angles  = (const float*)d_in[2];
    const int*   flip_h  = (const int*)d_in[3];
    const int*   flip_v  = (const int*)d_in[4];
    const float* scales  = (const float*)d_in[5];

    const int N = in_sizes[2];            // B*K = 256
    float* out   = (float*)d_out;
    float* out_p = out;                   // N*3*H*W
    float* out_l = out + (size_t)N * 3 * HW;

    int npatch_blocks = N * 3;            // 768: one per channel slice
    int nlabel_blocks = N;                // 256: one per label slice
    pa_all<<<npatch_blocks + nlabel_blocks, 1024, 0, stream>>>(
        patches, labels, angles, flip_h, flip_v, scales,
        out_p, out_l, npatch_blocks);
}